// Round 4
// baseline (2551.291 us; speedup 1.0000x reference)
//
#include <hip/hip_runtime.h>
#include <math.h>

// Problem constants
#define T_LEN  256
#define BATCH  32
#define EMBD   256
#define HHD    256           // per-direction hidden
#define NTAGS  12
#define NEGV   (-10000.0f)

// ---------------------------------------------------------------------------
// Kernel 1: zx = gather(embed)[m,:] @ [W_ih_f | W_ih_b]^T + bias
// M = 8192 rows (m = t*32 + b), N = 2048, K = 256. 128x128x16 tile.
// ---------------------------------------------------------------------------
__global__ __launch_bounds__(256) void gemm_zx(
    const int* __restrict__ sentence, const float* __restrict__ embed,
    const float* __restrict__ Wf,  const float* __restrict__ Wb,
    const float* __restrict__ bf,  const float* __restrict__ bb,
    float* __restrict__ zx)
{
    __shared__ float As[16][132];
    __shared__ float Bs[16][132];

    const int tid = threadIdx.x;
    const int tx = tid & 15, ty = tid >> 4;
    const int Mbase = (int)(blockIdx.x >> 4) * 128;
    const int Nbase = (int)(blockIdx.x & 15) * 128;

    const float* Wsrc = (Nbase < 1024) ? Wf : Wb;
    const float* bsrc = (Nbase < 1024) ? bf : bb;
    const int nOff = (Nbase < 1024) ? Nbase : (Nbase - 1024);

    const int m0 = tid >> 2;
    const int m1 = m0 + 64;
    const int kq = (tid & 3) * 4;
    const int mg0 = Mbase + m0, mg1 = Mbase + m1;
    const int tok0 = sentence[(mg0 & 31) * T_LEN + (mg0 >> 5)];
    const int tok1 = sentence[(mg1 & 31) * T_LEN + (mg1 >> 5)];
    const float* arow0 = embed + (long long)tok0 * EMBD;
    const float* arow1 = embed + (long long)tok1 * EMBD;
    const float* brow0 = Wsrc + (long long)(nOff + m0) * EMBD;
    const float* brow1 = Wsrc + (long long)(nOff + m1) * EMBD;

    float acc[8][8];
#pragma unroll
    for (int i = 0; i < 8; ++i)
#pragma unroll
        for (int j = 0; j < 8; ++j) acc[i][j] = 0.0f;

    for (int k0 = 0; k0 < EMBD; k0 += 16) {
        float4 av0 = *(const float4*)(arow0 + k0 + kq);
        float4 av1 = *(const float4*)(arow1 + k0 + kq);
        float4 bv0 = *(const float4*)(brow0 + k0 + kq);
        float4 bv1 = *(const float4*)(brow1 + k0 + kq);
        __syncthreads();
        As[kq+0][m0] = av0.x; As[kq+1][m0] = av0.y; As[kq+2][m0] = av0.z; As[kq+3][m0] = av0.w;
        As[kq+0][m1] = av1.x; As[kq+1][m1] = av1.y; As[kq+2][m1] = av1.z; As[kq+3][m1] = av1.w;
        Bs[kq+0][m0] = bv0.x; Bs[kq+1][m0] = bv0.y; Bs[kq+2][m0] = bv0.z; Bs[kq+3][m0] = bv0.w;
        Bs[kq+0][m1] = bv1.x; Bs[kq+1][m1] = bv1.y; Bs[kq+2][m1] = bv1.z; Bs[kq+3][m1] = bv1.w;
        __syncthreads();
#pragma unroll
        for (int kt = 0; kt < 16; ++kt) {
            float am[8], bn[8];
            *(float4*)&am[0] = *(const float4*)&As[kt][ty * 4];
            *(float4*)&am[4] = *(const float4*)&As[kt][64 + ty * 4];
            *(float4*)&bn[0] = *(const float4*)&Bs[kt][tx * 4];
            *(float4*)&bn[4] = *(const float4*)&Bs[kt][64 + tx * 4];
#pragma unroll
            for (int i = 0; i < 8; ++i)
#pragma unroll
                for (int j = 0; j < 8; ++j) acc[i][j] += am[i] * bn[j];
        }
    }

    float4 bias0 = *(const float4*)(bsrc + nOff + tx * 4);
    float4 bias1 = *(const float4*)(bsrc + nOff + 64 + tx * 4);
    const float bnv[8] = {bias0.x, bias0.y, bias0.z, bias0.w,
                          bias1.x, bias1.y, bias1.z, bias1.w};
#pragma unroll
    for (int i = 0; i < 8; ++i) {
        const int mg = Mbase + ty * 4 + (i & 3) + ((i >= 4) ? 64 : 0);
        float4 o0 = make_float4(acc[i][0] + bnv[0], acc[i][1] + bnv[1],
                                acc[i][2] + bnv[2], acc[i][3] + bnv[3]);
        float4 o1 = make_float4(acc[i][4] + bnv[4], acc[i][5] + bnv[5],
                                acc[i][6] + bnv[6], acc[i][7] + bnv[7]);
        *(float4*)(zx + (long long)mg * 2048 + Nbase + tx * 4) = o0;
        *(float4*)(zx + (long long)mg * 2048 + Nbase + 64 + tx * 4) = o1;
    }
}

// ---------------------------------------------------------------------------
// Kernel 1b: transpose W_hh (both dirs) to k-major WT[d][k][e][g] so the
// recurrence inner loop is a coalesced dwordx4 stream.
// WT[((d*256 + k)*256 + e)*4 + g] = W_hh_d[(g*256+e)*256 + k]
// ---------------------------------------------------------------------------
__global__ __launch_bounds__(256) void transpose_whh(
    const float* __restrict__ Whf, const float* __restrict__ Whb,
    float* __restrict__ WT)
{
    const int k = blockIdx.x & 255;
    const int d = blockIdx.x >> 8;
    const int e = threadIdx.x;
    const float* W = d ? Whb : Whf;
    float4 v;
    v.x = W[(0 * 256 + e) * 256 + k];
    v.y = W[(1 * 256 + e) * 256 + k];
    v.z = W[(2 * 256 + e) * 256 + k];
    v.w = W[(3 * 256 + e) * 256 + k];
    *(float4*)(WT + ((((long long)d * 256 + k) * 256 + e) << 2)) = v;
}

// ---------------------------------------------------------------------------
// Kernel 2: NO-SYNC chain LSTM. 64 WGs x 256 threads; WG = one (batch, dir)
// chain -> zero cross-WG communication, one LDS-local sync per step.
// d = bx&1: round-robin XCD placement gives each XCD 8 same-direction WGs
// sharing one resident 1 MB WT stream in its L2 (placement affects speed
// only, never correctness). Thread e owns h-element e: 4 gate accs over
// k with WT[k][e][0..3] dwordx4 (coalesced) x h[k] (LDS broadcast).
// c state in a register; h ping-pongs in LDS.
// ---------------------------------------------------------------------------
__global__ __launch_bounds__(256) void lstm_chain(
    const float* __restrict__ zx, const float* __restrict__ WT,
    const float* __restrict__ h0, const float* __restrict__ c0,
    float* __restrict__ lstm_out)
{
    __shared__ float hS[2][256];

    const int e = threadIdx.x;
    const int d = (int)(blockIdx.x & 1);
    const int b = (int)(blockIdx.x >> 1);
    const float* Wp = WT + (long long)d * 256 * 1024 + e * 4;   // [k][e][g]

    float creg = c0[(d * 32 + b) * 256 + e];
    hS[0][e] = h0[(d * 32 + b) * 256 + e];
    __syncthreads();

    for (int s = 0; s < T_LEN; ++s) {
        const int t = d ? (T_LEN - 1 - s) : s;

        // zx gate values for this (t,b,e) — issued early, consumed at end
        const float* zr = zx + (long long)(t * 32 + b) * 2048 + d * 1024 + e;
        const float z0 = zr[0], z1 = zr[256], z2 = zr[512], z3 = zr[768];

        const float* hrow = hS[s & 1];
        float a0 = 0.f, a1 = 0.f, a2 = 0.f, a3 = 0.f;
#pragma unroll 4
        for (int k = 0; k < 256; k += 4) {
            const float4 hv = *(const float4*)(hrow + k);        // broadcast
            const float4 w0 = *(const float4*)(Wp + (k + 0) * 1024);
            const float4 w1 = *(const float4*)(Wp + (k + 1) * 1024);
            const float4 w2 = *(const float4*)(Wp + (k + 2) * 1024);
            const float4 w3 = *(const float4*)(Wp + (k + 3) * 1024);
            a0 += w0.x * hv.x + w1.x * hv.y + w2.x * hv.z + w3.x * hv.w;
            a1 += w0.y * hv.x + w1.y * hv.y + w2.y * hv.z + w3.y * hv.w;
            a2 += w0.z * hv.x + w1.z * hv.y + w2.z * hv.z + w3.z * hv.w;
            a3 += w0.w * hv.x + w1.w * hv.y + w2.w * hv.z + w3.w * hv.w;
        }

        const float zi = a0 + z0, zf = a1 + z1, zg = a2 + z2, zo = a3 + z3;
        const float si = 1.0f / (1.0f + expf(-zi));
        const float sf = 1.0f / (1.0f + expf(-zf));
        const float so = 1.0f / (1.0f + expf(-zo));
        creg = sf * creg + si * tanhf(zg);
        const float hn = so * tanhf(creg);

        hS[(s & 1) ^ 1][e] = hn;
        lstm_out[(long long)(t * 32 + b) * 512 + d * 256 + e] = hn;
        __syncthreads();   // separates this step's hS reads from next writes
    }
}

// ---------------------------------------------------------------------------
// Kernel 3: feats = lstm_out @ W_out^T + b_out
// ---------------------------------------------------------------------------
__global__ __launch_bounds__(256) void feats_kernel(
    const float* __restrict__ lstm_out, const float* __restrict__ W_out,
    const float* __restrict__ b_out, float* __restrict__ feats)
{
    const int gid = blockIdx.x * 256 + threadIdx.x;
    if (gid >= 8192 * NTAGS) return;
    const int row = gid / NTAGS;
    const int tag = gid - row * NTAGS;
    const float4* x = (const float4*)(lstm_out + (long long)row * 512);
    const float4* w = (const float4*)(W_out + (long long)tag * 512);
    float acc = b_out[tag];
#pragma unroll 4
    for (int k = 0; k < 128; ++k) {
        float4 a = x[k], bw = w[k];
        acc += a.x * bw.x + a.y * bw.y + a.z * bw.z + a.w * bw.w;
    }
    const int t = row >> 5, b = row & 31;
    feats[(long long)b * (T_LEN * NTAGS) + t * NTAGS + tag] = acc;
}

// ---------------------------------------------------------------------------
// Kernel 4: Viterbi per batch. 32 WGs x 64 threads.
// ---------------------------------------------------------------------------
__global__ __launch_bounds__(64) void viterbi_kernel(
    const float* __restrict__ feats, const float* __restrict__ trans,
    float* __restrict__ out)
{
    __shared__ float featS[T_LEN * NTAGS];
    __shared__ float transS[NTAGS * NTAGS];
    __shared__ float fvS[NTAGS];
    __shared__ unsigned char bpS[T_LEN][NTAGS];
    __shared__ float pathS[T_LEN];

    const int b = blockIdx.x;
    const int lane = threadIdx.x;

    {
        const float4* src = (const float4*)(feats + (long long)b * (T_LEN * NTAGS));
        float4* dst = (float4*)featS;
        for (int i = lane; i < (T_LEN * NTAGS) / 4; i += 64) dst[i] = src[i];
        for (int i = lane; i < NTAGS * NTAGS; i += 64) transS[i] = trans[i];
    }
    __syncthreads();

    float fv[NTAGS];
#pragma unroll
    for (int p = 0; p < NTAGS; ++p) fv[p] = (p == 10) ? 0.0f : NEGV;

    for (int t = 0; t < T_LEN; ++t) {
        if (lane < NTAGS) {
            float best = -3.4e38f; int bi = 0;
#pragma unroll
            for (int p = 0; p < NTAGS; ++p) {
                const float v = fv[p] + transS[lane * NTAGS + p];
                if (v > best) { best = v; bi = p; }
            }
            bpS[t][lane] = (unsigned char)bi;
            fvS[lane] = best + featS[t * NTAGS + lane];
        }
        __syncthreads();
#pragma unroll
        for (int p = 0; p < NTAGS; ++p) fv[p] = fvS[p];
        __syncthreads();
    }

    if (lane < NTAGS) fvS[lane] = fv[lane] + transS[11 * NTAGS + lane];
    __syncthreads();
    if (lane == 0) {
        float best = -3.4e38f; int bi = 0;
        for (int p = 0; p < NTAGS; ++p) {
            const float v = fvS[p];
            if (v > best) { best = v; bi = p; }
        }
        out[b] = best;
        int cur = bi;
        pathS[T_LEN - 1] = (float)cur;
        for (int tt = T_LEN - 2; tt >= 0; --tt) {
            cur = bpS[tt + 1][cur];
            pathS[tt] = (float)cur;
        }
    }
    __syncthreads();
    float* po = out + BATCH + (long long)b * T_LEN;
    for (int i = lane; i < T_LEN; i += 64) po[i] = pathS[i];
}

// ---------------------------------------------------------------------------
extern "C" void kernel_launch(void* const* d_in, const int* in_sizes, int n_in,
                              void* d_out, int out_size, void* d_ws, size_t ws_size,
                              hipStream_t stream)
{
    (void)in_sizes; (void)n_in; (void)out_size; (void)ws_size;
    const int*   sentence = (const int*)  d_in[0];
    const float* embed    = (const float*)d_in[1];
    const float* W_ih_f   = (const float*)d_in[2];
    const float* W_hh_f   = (const float*)d_in[3];
    const float* b_f      = (const float*)d_in[4];
    const float* W_ih_b   = (const float*)d_in[5];
    const float* W_hh_b   = (const float*)d_in[6];
    const float* b_b      = (const float*)d_in[7];
    const float* W_out    = (const float*)d_in[8];
    const float* b_out    = (const float*)d_in[9];
    const float* trans    = (const float*)d_in[10];
    const float* h0       = (const float*)d_in[11];
    const float* c0       = (const float*)d_in[12];
    float* out = (float*)d_out;

    char* ws = (char*)d_ws;
    float* zx       = (float*)ws; ws += (long long)8192 * 2048 * 4;   // 64 MB
    float* lstm_out = (float*)ws; ws += (long long)8192 * 512 * 4;    // 16 MB
    float* feats    = (float*)ws; ws += BATCH * T_LEN * NTAGS * 4;    // 384 KB
    float* WT       = (float*)ws; ws += (long long)2 * 256 * 256 * 4 * 4; // 2 MB

    transpose_whh<<<512, 256, 0, stream>>>(W_hh_f, W_hh_b, WT);
    gemm_zx<<<1024, 256, 0, stream>>>(sentence, embed, W_ih_f, W_ih_b, b_f, b_b, zx);
    lstm_chain<<<64, 256, 0, stream>>>(zx, WT, h0, c0, lstm_out);
    feats_kernel<<<384, 256, 0, stream>>>(lstm_out, W_out, b_out, feats);
    viterbi_kernel<<<32, 64, 0, stream>>>(feats, trans, out);
}

// Round 5
// 1571.886 us; speedup vs baseline: 1.6231x; 1.6231x over previous
//
#include <hip/hip_runtime.h>
#include <math.h>

// Problem constants
#define T_LEN  256
#define BATCH  32
#define EMBD   256
#define HHD    256           // per-direction hidden
#define NTAGS  12
#define NEGV   (-10000.0f)

// ---------------------------------------------------------------------------
// Kernel 1: zx = gather(embed)[m,:] @ [W_ih_f | W_ih_b]^T + bias
// M = 8192 rows (m = t*32 + b), N = 2048, K = 256. 128x128x16 tile.
// ---------------------------------------------------------------------------
__global__ __launch_bounds__(256) void gemm_zx(
    const int* __restrict__ sentence, const float* __restrict__ embed,
    const float* __restrict__ Wf,  const float* __restrict__ Wb,
    const float* __restrict__ bf,  const float* __restrict__ bb,
    float* __restrict__ zx)
{
    __shared__ float As[16][132];
    __shared__ float Bs[16][132];

    const int tid = threadIdx.x;
    const int tx = tid & 15, ty = tid >> 4;
    const int Mbase = (int)(blockIdx.x >> 4) * 128;
    const int Nbase = (int)(blockIdx.x & 15) * 128;

    const float* Wsrc = (Nbase < 1024) ? Wf : Wb;
    const float* bsrc = (Nbase < 1024) ? bf : bb;
    const int nOff = (Nbase < 1024) ? Nbase : (Nbase - 1024);

    const int m0 = tid >> 2;
    const int m1 = m0 + 64;
    const int kq = (tid & 3) * 4;
    const int mg0 = Mbase + m0, mg1 = Mbase + m1;
    const int tok0 = sentence[(mg0 & 31) * T_LEN + (mg0 >> 5)];
    const int tok1 = sentence[(mg1 & 31) * T_LEN + (mg1 >> 5)];
    const float* arow0 = embed + (long long)tok0 * EMBD;
    const float* arow1 = embed + (long long)tok1 * EMBD;
    const float* brow0 = Wsrc + (long long)(nOff + m0) * EMBD;
    const float* brow1 = Wsrc + (long long)(nOff + m1) * EMBD;

    float acc[8][8];
#pragma unroll
    for (int i = 0; i < 8; ++i)
#pragma unroll
        for (int j = 0; j < 8; ++j) acc[i][j] = 0.0f;

    for (int k0 = 0; k0 < EMBD; k0 += 16) {
        float4 av0 = *(const float4*)(arow0 + k0 + kq);
        float4 av1 = *(const float4*)(arow1 + k0 + kq);
        float4 bv0 = *(const float4*)(brow0 + k0 + kq);
        float4 bv1 = *(const float4*)(brow1 + k0 + kq);
        __syncthreads();
        As[kq+0][m0] = av0.x; As[kq+1][m0] = av0.y; As[kq+2][m0] = av0.z; As[kq+3][m0] = av0.w;
        As[kq+0][m1] = av1.x; As[kq+1][m1] = av1.y; As[kq+2][m1] = av1.z; As[kq+3][m1] = av1.w;
        Bs[kq+0][m0] = bv0.x; Bs[kq+1][m0] = bv0.y; Bs[kq+2][m0] = bv0.z; Bs[kq+3][m0] = bv0.w;
        Bs[kq+0][m1] = bv1.x; Bs[kq+1][m1] = bv1.y; Bs[kq+2][m1] = bv1.z; Bs[kq+3][m1] = bv1.w;
        __syncthreads();
#pragma unroll
        for (int kt = 0; kt < 16; ++kt) {
            float am[8], bn[8];
            *(float4*)&am[0] = *(const float4*)&As[kt][ty * 4];
            *(float4*)&am[4] = *(const float4*)&As[kt][64 + ty * 4];
            *(float4*)&bn[0] = *(const float4*)&Bs[kt][tx * 4];
            *(float4*)&bn[4] = *(const float4*)&Bs[kt][64 + tx * 4];
#pragma unroll
            for (int i = 0; i < 8; ++i)
#pragma unroll
                for (int j = 0; j < 8; ++j) acc[i][j] += am[i] * bn[j];
        }
    }

    float4 bias0 = *(const float4*)(bsrc + nOff + tx * 4);
    float4 bias1 = *(const float4*)(bsrc + nOff + 64 + tx * 4);
    const float bnv[8] = {bias0.x, bias0.y, bias0.z, bias0.w,
                          bias1.x, bias1.y, bias1.z, bias1.w};
#pragma unroll
    for (int i = 0; i < 8; ++i) {
        const int mg = Mbase + ty * 4 + (i & 3) + ((i >= 4) ? 64 : 0);
        float4 o0 = make_float4(acc[i][0] + bnv[0], acc[i][1] + bnv[1],
                                acc[i][2] + bnv[2], acc[i][3] + bnv[3]);
        float4 o1 = make_float4(acc[i][4] + bnv[4], acc[i][5] + bnv[5],
                                acc[i][6] + bnv[6], acc[i][7] + bnv[7]);
        *(float4*)(zx + (long long)mg * 2048 + Nbase + tx * 4) = o0;
        *(float4*)(zx + (long long)mg * 2048 + Nbase + 64 + tx * 4) = o1;
    }
}

// ---------------------------------------------------------------------------
// Kernel 1b: pack W_hh into per-WG row-major slices:
// pack[d][q][j][k], j = gate-row (g = j>>6, e = q*64 + (j&63)).
// Each lstm_team WG (d,b,q) thread tid later register-loads row j=tid.
// ---------------------------------------------------------------------------
__global__ __launch_bounds__(256) void pack_whh(
    const float* __restrict__ Whf, const float* __restrict__ Whb,
    float* __restrict__ pack)
{
    const int gid = blockIdx.x * 256 + threadIdx.x;   // 0..524287
    const int k  = gid & 255;
    const int j  = (gid >> 8) & 255;
    const int q  = (gid >> 16) & 3;
    const int d  = (gid >> 18) & 1;
    const float* W = d ? Whb : Whf;
    const int g = j >> 6;
    const int e = q * 64 + (j & 63);
    pack[gid] = W[(g * 256 + e) * 256 + k];
}

// ---------------------------------------------------------------------------
// Kernel 2: REGISTER-RESIDENT team LSTM. 256 WGs x 256 threads.
// bx = (b*2 + d)*4 + q  ->  q = bx&3, d = (bx>>2)&1, b = bx>>3.
// Team = 4 WGs per chain (d,b); WG q owns e-range [q*64, q*64+64).
// Thread tid owns gate-row j=tid (g = tid>>6, e = q*64 + (tid&63)); its
// 1 KB W-row lives in 64 float4 REGISTERS -> zero W memory traffic/step.
// 80 KB LDS block forces exactly 1 WG/CU => all 256 WGs co-resident.
// h exchange: tagged u64 {step, f32} ping-pong via relaxed AGENT atomics
// (data+tag one word: no fence). Each thread polls exactly ONE slot.
// Overwrite distance 2 + all WGs both produce & consume => safe (R2 proof).
// c state in registers of threads 0..63.
// ---------------------------------------------------------------------------
__global__ __launch_bounds__(256, 1) void lstm_team(
    const float* __restrict__ zx, const float* __restrict__ pack,
    const float* __restrict__ h0, const float* __restrict__ c0,
    unsigned long long* __restrict__ hx,   // [2 par][2 d][32 b][256 e]
    float* __restrict__ lstm_out)
{
    __shared__ float smem[20480];          // 80 KB -> 1 WG/CU guaranteed
    float* hS0 = smem;                     // h parity 0 [256]
    float* hS1 = smem + 256;               // h parity 1 [256]
    float* zS  = smem + 512;               // z values  [256]

    const int tid = threadIdx.x;
    const int bx  = (int)blockIdx.x;
    const int q = bx & 3, d = (bx >> 2) & 1, b = bx >> 3;

    // --- W row into registers (one-time) ---
    float4 wreg[64];
    {
        const float4* wrow = (const float4*)(pack + ((long long)(bx & 7) << 16)
                                             + tid * 256);
#pragma unroll
        for (int c = 0; c < 64; ++c) wreg[c] = wrow[c];
    }

    const int own  = ((tid >> 6) == q);            // this thread's poll target is team-local
    const int zoff = d * 1024 + (tid >> 6) * 256 + q * 64 + (tid & 63);
    float creg = (tid < 64) ? c0[(d * 32 + b) * 256 + q * 64 + tid] : 0.0f;
    const long long hxbase = (long long)(d * 32 + b) * 256;

    hS0[tid] = h0[(d * 32 + b) * 256 + tid];
    __syncthreads();

    for (int s = 0; s < T_LEN; ++s) {
        const int t = d ? (T_LEN - 1 - s) : s;
        const float zv = zx[(long long)(t * 32 + b) * 2048 + zoff];
        const float* h  = (s & 1) ? hS1 : hS0;
        float*       hN = (s & 1) ? hS0 : hS1;

        // --- dot(W_row, h_prev): W from registers, h broadcast from LDS ---
        float a = 0.0f;
#pragma unroll
        for (int c = 0; c < 64; ++c) {
            const float4 hv = *(const float4*)(h + c * 4);
            a += wreg[c].x * hv.x + wreg[c].y * hv.y
               + wreg[c].z * hv.z + wreg[c].w * hv.w;
        }
        zS[tid] = a + zv;
        __syncthreads();

        const int parN = (s & 1) ^ 1;
        if (tid < 64) {
            const float zi = zS[tid],       zf = zS[64 + tid],
                        zg = zS[128 + tid], zo = zS[192 + tid];
            const float si = 1.0f / (1.0f + expf(-zi));
            const float sf = 1.0f / (1.0f + expf(-zf));
            const float so = 1.0f / (1.0f + expf(-zo));
            creg = sf * creg + si * tanhf(zg);
            const float hn = so * tanhf(creg);
            const int e = q * 64 + tid;
            hN[e] = hn;
            lstm_out[(long long)(t * 32 + b) * 512 + d * 256 + e] = hn;
            __hip_atomic_store(hx + (long long)parN * 16384 + hxbase + e,
                ((unsigned long long)(unsigned)(s + 1) << 32)
                    | (unsigned long long)__float_as_uint(hn),
                __ATOMIC_RELAXED, __HIP_MEMORY_SCOPE_AGENT);
        }
        // --- fetch partners' h for next step: ONE slot per thread ---
        if (s < T_LEN - 1 && !own) {
            const unsigned long long* slot =
                hx + (long long)parN * 16384 + hxbase + tid;
            unsigned long long v;
            do {
                v = __hip_atomic_load(slot, __ATOMIC_RELAXED,
                                      __HIP_MEMORY_SCOPE_AGENT);
            } while ((unsigned)(v >> 32) != (unsigned)(s + 1));
            hN[tid] = __uint_as_float((unsigned)v);
        }
        __syncthreads();
    }
}

// ---------------------------------------------------------------------------
// Kernel 3: feats = lstm_out @ W_out^T + b_out
// ---------------------------------------------------------------------------
__global__ __launch_bounds__(256) void feats_kernel(
    const float* __restrict__ lstm_out, const float* __restrict__ W_out,
    const float* __restrict__ b_out, float* __restrict__ feats)
{
    const int gid = blockIdx.x * 256 + threadIdx.x;
    if (gid >= 8192 * NTAGS) return;
    const int row = gid / NTAGS;
    const int tag = gid - row * NTAGS;
    const float4* x = (const float4*)(lstm_out + (long long)row * 512);
    const float4* w = (const float4*)(W_out + (long long)tag * 512);
    float acc = b_out[tag];
#pragma unroll 4
    for (int k = 0; k < 128; ++k) {
        float4 a = x[k], bw = w[k];
        acc += a.x * bw.x + a.y * bw.y + a.z * bw.z + a.w * bw.w;
    }
    const int t = row >> 5, b = row & 31;
    feats[(long long)b * (T_LEN * NTAGS) + t * NTAGS + tag] = acc;
}

// ---------------------------------------------------------------------------
// Kernel 4: Viterbi per batch. 32 WGs x 64 threads.
// ---------------------------------------------------------------------------
__global__ __launch_bounds__(64) void viterbi_kernel(
    const float* __restrict__ feats, const float* __restrict__ trans,
    float* __restrict__ out)
{
    __shared__ float featS[T_LEN * NTAGS];
    __shared__ float transS[NTAGS * NTAGS];
    __shared__ float fvS[NTAGS];
    __shared__ unsigned char bpS[T_LEN][NTAGS];
    __shared__ float pathS[T_LEN];

    const int b = blockIdx.x;
    const int lane = threadIdx.x;

    {
        const float4* src = (const float4*)(feats + (long long)b * (T_LEN * NTAGS));
        float4* dst = (float4*)featS;
        for (int i = lane; i < (T_LEN * NTAGS) / 4; i += 64) dst[i] = src[i];
        for (int i = lane; i < NTAGS * NTAGS; i += 64) transS[i] = trans[i];
    }
    __syncthreads();

    float fv[NTAGS];
#pragma unroll
    for (int p = 0; p < NTAGS; ++p) fv[p] = (p == 10) ? 0.0f : NEGV;

    for (int t = 0; t < T_LEN; ++t) {
        if (lane < NTAGS) {
            float best = -3.4e38f; int bi = 0;
#pragma unroll
            for (int p = 0; p < NTAGS; ++p) {
                const float v = fv[p] + transS[lane * NTAGS + p];
                if (v > best) { best = v; bi = p; }
            }
            bpS[t][lane] = (unsigned char)bi;
            fvS[lane] = best + featS[t * NTAGS + lane];
        }
        __syncthreads();
#pragma unroll
        for (int p = 0; p < NTAGS; ++p) fv[p] = fvS[p];
        __syncthreads();
    }

    if (lane < NTAGS) fvS[lane] = fv[lane] + transS[11 * NTAGS + lane];
    __syncthreads();
    if (lane == 0) {
        float best = -3.4e38f; int bi = 0;
        for (int p = 0; p < NTAGS; ++p) {
            const float v = fvS[p];
            if (v > best) { best = v; bi = p; }
        }
        out[b] = best;
        int cur = bi;
        pathS[T_LEN - 1] = (float)cur;
        for (int tt = T_LEN - 2; tt >= 0; --tt) {
            cur = bpS[tt + 1][cur];
            pathS[tt] = (float)cur;
        }
    }
    __syncthreads();
    float* po = out + BATCH + (long long)b * T_LEN;
    for (int i = lane; i < T_LEN; i += 64) po[i] = pathS[i];
}

// ---------------------------------------------------------------------------
extern "C" void kernel_launch(void* const* d_in, const int* in_sizes, int n_in,
                              void* d_out, int out_size, void* d_ws, size_t ws_size,
                              hipStream_t stream)
{
    (void)in_sizes; (void)n_in; (void)out_size; (void)ws_size;
    const int*   sentence = (const int*)  d_in[0];
    const float* embed    = (const float*)d_in[1];
    const float* W_ih_f   = (const float*)d_in[2];
    const float* W_hh_f   = (const float*)d_in[3];
    const float* b_f      = (const float*)d_in[4];
    const float* W_ih_b   = (const float*)d_in[5];
    const float* W_hh_b   = (const float*)d_in[6];
    const float* b_b      = (const float*)d_in[7];
    const float* W_out    = (const float*)d_in[8];
    const float* b_out    = (const float*)d_in[9];
    const float* trans    = (const float*)d_in[10];
    const float* h0       = (const float*)d_in[11];
    const float* c0       = (const float*)d_in[12];
    float* out = (float*)d_out;

    char* ws = (char*)d_ws;
    float* zx       = (float*)ws; ws += (long long)8192 * 2048 * 4;   // 64 MB
    float* lstm_out = (float*)ws; ws += (long long)8192 * 512 * 4;    // 16 MB
    float* feats    = (float*)ws; ws += BATCH * T_LEN * NTAGS * 4;    // 384 KB
    float* pack     = (float*)ws; ws += (long long)524288 * 4;        // 2 MB
    unsigned long long* hx = (unsigned long long*)ws; ws += 2 * 16384 * 8; // 256 KB
    // hx re-poisoned to 0xAA before every launch -> tags invalid. No memset.

    pack_whh<<<2048, 256, 0, stream>>>(W_hh_f, W_hh_b, pack);
    gemm_zx<<<1024, 256, 0, stream>>>(sentence, embed, W_ih_f, W_ih_b, b_f, b_b, zx);
    lstm_team<<<256, 256, 0, stream>>>(zx, pack, h0, c0, hx, lstm_out);
    feats_kernel<<<384, 256, 0, stream>>>(lstm_out, W_out, b_out, feats);
    viterbi_kernel<<<32, 64, 0, stream>>>(feats, trans, out);
}

// Round 6
// 892.095 us; speedup vs baseline: 2.8599x; 1.7620x over previous
//
#include <hip/hip_runtime.h>
#include <math.h>

// Problem constants
#define T_LEN  256
#define BATCH  32
#define EMBD   256
#define HHD    256           // per-direction hidden
#define NTAGS  12
#define NEGV   (-10000.0f)

// ---------------------------------------------------------------------------
// Kernel 1: zx = gather(embed)[m,:] @ [W_ih_f | W_ih_b]^T + bias
// M = 8192 rows (m = t*32 + b), N = 2048, K = 256. 128x128x16 tile.
// ---------------------------------------------------------------------------
__global__ __launch_bounds__(256) void gemm_zx(
    const int* __restrict__ sentence, const float* __restrict__ embed,
    const float* __restrict__ Wf,  const float* __restrict__ Wb,
    const float* __restrict__ bf,  const float* __restrict__ bb,
    float* __restrict__ zx)
{
    __shared__ float As[16][132];
    __shared__ float Bs[16][132];

    const int tid = threadIdx.x;
    const int tx = tid & 15, ty = tid >> 4;
    const int Mbase = (int)(blockIdx.x >> 4) * 128;
    const int Nbase = (int)(blockIdx.x & 15) * 128;

    const float* Wsrc = (Nbase < 1024) ? Wf : Wb;
    const float* bsrc = (Nbase < 1024) ? bf : bb;
    const int nOff = (Nbase < 1024) ? Nbase : (Nbase - 1024);

    const int m0 = tid >> 2;
    const int m1 = m0 + 64;
    const int kq = (tid & 3) * 4;
    const int mg0 = Mbase + m0, mg1 = Mbase + m1;
    const int tok0 = sentence[(mg0 & 31) * T_LEN + (mg0 >> 5)];
    const int tok1 = sentence[(mg1 & 31) * T_LEN + (mg1 >> 5)];
    const float* arow0 = embed + (long long)tok0 * EMBD;
    const float* arow1 = embed + (long long)tok1 * EMBD;
    const float* brow0 = Wsrc + (long long)(nOff + m0) * EMBD;
    const float* brow1 = Wsrc + (long long)(nOff + m1) * EMBD;

    float acc[8][8];
#pragma unroll
    for (int i = 0; i < 8; ++i)
#pragma unroll
        for (int j = 0; j < 8; ++j) acc[i][j] = 0.0f;

    for (int k0 = 0; k0 < EMBD; k0 += 16) {
        float4 av0 = *(const float4*)(arow0 + k0 + kq);
        float4 av1 = *(const float4*)(arow1 + k0 + kq);
        float4 bv0 = *(const float4*)(brow0 + k0 + kq);
        float4 bv1 = *(const float4*)(brow1 + k0 + kq);
        __syncthreads();
        As[kq+0][m0] = av0.x; As[kq+1][m0] = av0.y; As[kq+2][m0] = av0.z; As[kq+3][m0] = av0.w;
        As[kq+0][m1] = av1.x; As[kq+1][m1] = av1.y; As[kq+2][m1] = av1.z; As[kq+3][m1] = av1.w;
        Bs[kq+0][m0] = bv0.x; Bs[kq+1][m0] = bv0.y; Bs[kq+2][m0] = bv0.z; Bs[kq+3][m0] = bv0.w;
        Bs[kq+0][m1] = bv1.x; Bs[kq+1][m1] = bv1.y; Bs[kq+2][m1] = bv1.z; Bs[kq+3][m1] = bv1.w;
        __syncthreads();
#pragma unroll
        for (int kt = 0; kt < 16; ++kt) {
            float am[8], bn[8];
            *(float4*)&am[0] = *(const float4*)&As[kt][ty * 4];
            *(float4*)&am[4] = *(const float4*)&As[kt][64 + ty * 4];
            *(float4*)&bn[0] = *(const float4*)&Bs[kt][tx * 4];
            *(float4*)&bn[4] = *(const float4*)&Bs[kt][64 + tx * 4];
#pragma unroll
            for (int i = 0; i < 8; ++i)
#pragma unroll
                for (int j = 0; j < 8; ++j) acc[i][j] += am[i] * bn[j];
        }
    }

    float4 bias0 = *(const float4*)(bsrc + nOff + tx * 4);
    float4 bias1 = *(const float4*)(bsrc + nOff + 64 + tx * 4);
    const float bnv[8] = {bias0.x, bias0.y, bias0.z, bias0.w,
                          bias1.x, bias1.y, bias1.z, bias1.w};
#pragma unroll
    for (int i = 0; i < 8; ++i) {
        const int mg = Mbase + ty * 4 + (i & 3) + ((i >= 4) ? 64 : 0);
        float4 o0 = make_float4(acc[i][0] + bnv[0], acc[i][1] + bnv[1],
                                acc[i][2] + bnv[2], acc[i][3] + bnv[3]);
        float4 o1 = make_float4(acc[i][4] + bnv[4], acc[i][5] + bnv[5],
                                acc[i][6] + bnv[6], acc[i][7] + bnv[7]);
        *(float4*)(zx + (long long)mg * 2048 + Nbase + tx * 4) = o0;
        *(float4*)(zx + (long long)mg * 2048 + Nbase + 64 + tx * 4) = o1;
    }
}

// ---------------------------------------------------------------------------
// Kernel 1b: pack W_hh into per-(WG,thread) contiguous 512 B chunks:
// offset = (((d*4+q)*2 + half)*256 + j)*128 + k2
//   j = gate-row within WG (g = j>>6, e = q*64 + (j&63)), k = half*128+k2.
// lstm_team WG bx (bx&7 = d*4+q) thread tid reads chunk at tid*128.
// ---------------------------------------------------------------------------
__global__ __launch_bounds__(256) void pack_whh(
    const float* __restrict__ Whf, const float* __restrict__ Whb,
    float* __restrict__ pack)
{
    const int gid = blockIdx.x * 256 + threadIdx.x;   // 0..524287
    const int k2   = gid & 127;
    const int j    = (gid >> 7) & 255;
    const int half = (gid >> 15) & 1;
    const int q    = (gid >> 16) & 3;
    const int d    = (gid >> 18) & 1;
    const float* W = d ? Whb : Whf;
    const int g = j >> 6;
    const int e = q * 64 + (j & 63);
    pack[gid] = W[(g * 256 + e) * 256 + half * 128 + k2];
}

// ---------------------------------------------------------------------------
// Kernel 2: REGISTER-RESIDENT team LSTM, spill-proof edition.
// 256 WGs x 512 threads; bx: q = bx&3 (e-quarter), d = (bx>>2)&1, b = bx>>3.
// Team = 4 WGs per (b,d) chain. Thread tid: half = tid>>8, j = tid&255;
// owns HALF a gate-row = 32 float4 in registers (~170 VGPR total, under the
// launch_bounds(512,2) 256-VGPR cap -> no spill; >=136 VGPR also forces
// 1 WG/CU so all 256 WGs are co-resident; at 2 WG/CU they still all fit).
// Step: dot -> pS[tid]; sync; wave0 = gates+publish (tagged u64, relaxed
// AGENT atomics, ping-pong parity — R2/R4-proven safety), waves 1-3 poll
// e in [64,256) (skip own quarter), wave4 polls e in [0,64) when q!=0;
// each thread polls exactly ONE slot; sync. c state in wave-0 registers.
// ---------------------------------------------------------------------------
__global__ __launch_bounds__(512, 2) void lstm_team(
    const float* __restrict__ zx, const float* __restrict__ pack,
    const float* __restrict__ h0, const float* __restrict__ c0,
    unsigned long long* __restrict__ hx,   // [2 par][2 d][32 b][256 e]
    float* __restrict__ lstm_out)
{
    __shared__ float hS0[256];
    __shared__ float hS1[256];
    __shared__ float pS[512];

    const int tid = threadIdx.x;
    const int bx  = (int)blockIdx.x;
    const int q = bx & 3, d = (bx >> 2) & 1, b = bx >> 3;

    // --- W half-row into registers (one-time, coalesced) ---
    float4 wreg[32];
    {
        const float4* wrow = (const float4*)(pack + ((long long)(bx & 7) << 16)
                                             + tid * 128);
#pragma unroll
        for (int c = 0; c < 32; ++c) wreg[c] = wrow[c];
    }

    const int half = tid >> 8;            // k-half this thread dots
    const int j    = tid & 255;           // gate-row within WG
    const long long hxbase = (long long)(d * 32 + b) * 256;
    // gate thread (tid<64) zx row base: gate g at +g*256
    const long long zbase = (long long)d * 1024 + q * 64 + (tid & 63);
    float creg = (tid < 64) ? c0[(d * 32 + b) * 256 + q * 64 + tid] : 0.0f;

    if (tid < 256) hS0[tid] = h0[(d * 32 + b) * 256 + tid];
    __syncthreads();

    for (int s = 0; s < T_LEN; ++s) {
        const int t = d ? (T_LEN - 1 - s) : s;

        // zx prefetch for gate wave (issued before dot; vmcnt hides latency)
        float zv0 = 0.f, zv1 = 0.f, zv2 = 0.f, zv3 = 0.f;
        if (tid < 64) {
            const float* zr = zx + (long long)(t * 32 + b) * 2048 + zbase;
            zv0 = zr[0]; zv1 = zr[256]; zv2 = zr[512]; zv3 = zr[768];
        }

        const float* h  = (s & 1) ? hS1 : hS0;
        float*       hN = (s & 1) ? hS0 : hS1;
        const float* hh = h + half * 128;

        // --- half-dot from registers ---
        float a = 0.0f;
#pragma unroll
        for (int c = 0; c < 32; ++c) {
            const float4 hv = *(const float4*)(hh + c * 4);
            a += wreg[c].x * hv.x + wreg[c].y * hv.y
               + wreg[c].z * hv.z + wreg[c].w * hv.w;
        }
        pS[tid] = a;
        __syncthreads();

        const int parN = (s & 1) ^ 1;
        if (tid < 64) {
            // combine halves + zx for this e's 4 gate rows
            const float zi = pS[tid]       + pS[tid + 256]       + zv0;
            const float zf = pS[tid + 64]  + pS[tid + 320]       + zv1;
            const float zg = pS[tid + 128] + pS[tid + 384]       + zv2;
            const float zo = pS[tid + 192] + pS[tid + 448]       + zv3;
            const float si = 1.0f / (1.0f + expf(-zi));
            const float sf = 1.0f / (1.0f + expf(-zf));
            const float so = 1.0f / (1.0f + expf(-zo));
            creg = sf * creg + si * tanhf(zg);
            const float hn = so * tanhf(creg);
            const int e = q * 64 + tid;
            hN[e] = hn;
            lstm_out[(long long)(t * 32 + b) * 512 + d * 256 + e] = hn;
            __hip_atomic_store(hx + (long long)parN * 16384 + hxbase + e,
                ((unsigned long long)(unsigned)(s + 1) << 32)
                    | (unsigned long long)__float_as_uint(hn),
                __ATOMIC_RELAXED, __HIP_MEMORY_SCOPE_AGENT);
        } else if (s < T_LEN - 1) {
            int e = -1;
            if (tid < 256) { if ((tid >> 6) != q) e = tid; }
            else if (tid < 320) { if (q != 0) e = tid - 256; }
            if (e >= 0) {
                const unsigned long long* slot =
                    hx + (long long)parN * 16384 + hxbase + e;
                unsigned long long v;
                do {
                    v = __hip_atomic_load(slot, __ATOMIC_RELAXED,
                                          __HIP_MEMORY_SCOPE_AGENT);
                } while ((unsigned)(v >> 32) != (unsigned)(s + 1));
                hN[e] = __uint_as_float((unsigned)v);
            }
        }
        __syncthreads();
    }
}

// ---------------------------------------------------------------------------
// Kernel 3: feats = lstm_out @ W_out^T + b_out
// ---------------------------------------------------------------------------
__global__ __launch_bounds__(256) void feats_kernel(
    const float* __restrict__ lstm_out, const float* __restrict__ W_out,
    const float* __restrict__ b_out, float* __restrict__ feats)
{
    const int gid = blockIdx.x * 256 + threadIdx.x;
    if (gid >= 8192 * NTAGS) return;
    const int row = gid / NTAGS;
    const int tag = gid - row * NTAGS;
    const float4* x = (const float4*)(lstm_out + (long long)row * 512);
    const float4* w = (const float4*)(W_out + (long long)tag * 512);
    float acc = b_out[tag];
#pragma unroll 4
    for (int k = 0; k < 128; ++k) {
        float4 a = x[k], bw = w[k];
        acc += a.x * bw.x + a.y * bw.y + a.z * bw.z + a.w * bw.w;
    }
    const int t = row >> 5, b = row & 31;
    feats[(long long)b * (T_LEN * NTAGS) + t * NTAGS + tag] = acc;
}

// ---------------------------------------------------------------------------
// Kernel 4: Viterbi per batch. 32 WGs x 64 threads.
// ---------------------------------------------------------------------------
__global__ __launch_bounds__(64) void viterbi_kernel(
    const float* __restrict__ feats, const float* __restrict__ trans,
    float* __restrict__ out)
{
    __shared__ float featS[T_LEN * NTAGS];
    __shared__ float transS[NTAGS * NTAGS];
    __shared__ float fvS[NTAGS];
    __shared__ unsigned char bpS[T_LEN][NTAGS];
    __shared__ float pathS[T_LEN];

    const int b = blockIdx.x;
    const int lane = threadIdx.x;

    {
        const float4* src = (const float4*)(feats + (long long)b * (T_LEN * NTAGS));
        float4* dst = (float4*)featS;
        for (int i = lane; i < (T_LEN * NTAGS) / 4; i += 64) dst[i] = src[i];
        for (int i = lane; i < NTAGS * NTAGS; i += 64) transS[i] = trans[i];
    }
    __syncthreads();

    float fv[NTAGS];
#pragma unroll
    for (int p = 0; p < NTAGS; ++p) fv[p] = (p == 10) ? 0.0f : NEGV;

    for (int t = 0; t < T_LEN; ++t) {
        if (lane < NTAGS) {
            float best = -3.4e38f; int bi = 0;
#pragma unroll
            for (int p = 0; p < NTAGS; ++p) {
                const float v = fv[p] + transS[lane * NTAGS + p];
                if (v > best) { best = v; bi = p; }
            }
            bpS[t][lane] = (unsigned char)bi;
            fvS[lane] = best + featS[t * NTAGS + lane];
        }
        __syncthreads();
#pragma unroll
        for (int p = 0; p < NTAGS; ++p) fv[p] = fvS[p];
        __syncthreads();
    }

    if (lane < NTAGS) fvS[lane] = fv[lane] + transS[11 * NTAGS + lane];
    __syncthreads();
    if (lane == 0) {
        float best = -3.4e38f; int bi = 0;
        for (int p = 0; p < NTAGS; ++p) {
            const float v = fvS[p];
            if (v > best) { best = v; bi = p; }
        }
        out[b] = best;
        int cur = bi;
        pathS[T_LEN - 1] = (float)cur;
        for (int tt = T_LEN - 2; tt >= 0; --tt) {
            cur = bpS[tt + 1][cur];
            pathS[tt] = (float)cur;
        }
    }
    __syncthreads();
    float* po = out + BATCH + (long long)b * T_LEN;
    for (int i = lane; i < T_LEN; i += 64) po[i] = pathS[i];
}

// ---------------------------------------------------------------------------
extern "C" void kernel_launch(void* const* d_in, const int* in_sizes, int n_in,
                              void* d_out, int out_size, void* d_ws, size_t ws_size,
                              hipStream_t stream)
{
    (void)in_sizes; (void)n_in; (void)out_size; (void)ws_size;
    const int*   sentence = (const int*)  d_in[0];
    const float* embed    = (const float*)d_in[1];
    const float* W_ih_f   = (const float*)d_in[2];
    const float* W_hh_f   = (const float*)d_in[3];
    const float* b_f      = (const float*)d_in[4];
    const float* W_ih_b   = (const float*)d_in[5];
    const float* W_hh_b   = (const float*)d_in[6];
    const float* b_b      = (const float*)d_in[7];
    const float* W_out    = (const float*)d_in[8];
    const float* b_out    = (const float*)d_in[9];
    const float* trans    = (const float*)d_in[10];
    const float* h0       = (const float*)d_in[11];
    const float* c0       = (const float*)d_in[12];
    float* out = (float*)d_out;

    char* ws = (char*)d_ws;
    float* zx       = (float*)ws; ws += (long long)8192 * 2048 * 4;   // 64 MB
    float* lstm_out = (float*)ws; ws += (long long)8192 * 512 * 4;    // 16 MB
    float* feats    = (float*)ws; ws += BATCH * T_LEN * NTAGS * 4;    // 384 KB
    float* pack     = (float*)ws; ws += (long long)524288 * 4;        // 2 MB
    unsigned long long* hx = (unsigned long long*)ws; ws += 2 * 16384 * 8; // 256 KB
    // hx re-poisoned to 0xAA before every launch -> tags invalid. No memset.

    pack_whh<<<2048, 256, 0, stream>>>(W_hh_f, W_hh_b, pack);
    gemm_zx<<<1024, 256, 0, stream>>>(sentence, embed, W_ih_f, W_ih_b, b_f, b_b, zx);
    lstm_team<<<256, 512, 0, stream>>>(zx, pack, h0, c0, hx, lstm_out);
    feats_kernel<<<384, 256, 0, stream>>>(lstm_out, W_out, b_out, feats);
    viterbi_kernel<<<32, 64, 0, stream>>>(feats, trans, out);
}

// Round 7
// 890.524 us; speedup vs baseline: 2.8649x; 1.0018x over previous
//
#include <hip/hip_runtime.h>
#include <math.h>

// Problem constants
#define T_LEN  256
#define BATCH  32
#define EMBD   256
#define HHD    256           // per-direction hidden
#define NTAGS  12
#define NEGV   (-10000.0f)

// ---------------------------------------------------------------------------
// Kernel 1: zx = gather(embed)[m,:] @ [W_ih_f | W_ih_b]^T + bias
// M = 8192 rows (m = t*32 + b), N = 2048, K = 256. 128x128x16 tile.
// ---------------------------------------------------------------------------
__global__ __launch_bounds__(256) void gemm_zx(
    const int* __restrict__ sentence, const float* __restrict__ embed,
    const float* __restrict__ Wf,  const float* __restrict__ Wb,
    const float* __restrict__ bf,  const float* __restrict__ bb,
    float* __restrict__ zx)
{
    __shared__ float As[16][132];
    __shared__ float Bs[16][132];

    const int tid = threadIdx.x;
    const int tx = tid & 15, ty = tid >> 4;
    const int Mbase = (int)(blockIdx.x >> 4) * 128;
    const int Nbase = (int)(blockIdx.x & 15) * 128;

    const float* Wsrc = (Nbase < 1024) ? Wf : Wb;
    const float* bsrc = (Nbase < 1024) ? bf : bb;
    const int nOff = (Nbase < 1024) ? Nbase : (Nbase - 1024);

    const int m0 = tid >> 2;
    const int m1 = m0 + 64;
    const int kq = (tid & 3) * 4;
    const int mg0 = Mbase + m0, mg1 = Mbase + m1;
    const int tok0 = sentence[(mg0 & 31) * T_LEN + (mg0 >> 5)];
    const int tok1 = sentence[(mg1 & 31) * T_LEN + (mg1 >> 5)];
    const float* arow0 = embed + (long long)tok0 * EMBD;
    const float* arow1 = embed + (long long)tok1 * EMBD;
    const float* brow0 = Wsrc + (long long)(nOff + m0) * EMBD;
    const float* brow1 = Wsrc + (long long)(nOff + m1) * EMBD;

    float acc[8][8];
#pragma unroll
    for (int i = 0; i < 8; ++i)
#pragma unroll
        for (int j = 0; j < 8; ++j) acc[i][j] = 0.0f;

    for (int k0 = 0; k0 < EMBD; k0 += 16) {
        float4 av0 = *(const float4*)(arow0 + k0 + kq);
        float4 av1 = *(const float4*)(arow1 + k0 + kq);
        float4 bv0 = *(const float4*)(brow0 + k0 + kq);
        float4 bv1 = *(const float4*)(brow1 + k0 + kq);
        __syncthreads();
        As[kq+0][m0] = av0.x; As[kq+1][m0] = av0.y; As[kq+2][m0] = av0.z; As[kq+3][m0] = av0.w;
        As[kq+0][m1] = av1.x; As[kq+1][m1] = av1.y; As[kq+2][m1] = av1.z; As[kq+3][m1] = av1.w;
        Bs[kq+0][m0] = bv0.x; Bs[kq+1][m0] = bv0.y; Bs[kq+2][m0] = bv0.z; Bs[kq+3][m0] = bv0.w;
        Bs[kq+0][m1] = bv1.x; Bs[kq+1][m1] = bv1.y; Bs[kq+2][m1] = bv1.z; Bs[kq+3][m1] = bv1.w;
        __syncthreads();
#pragma unroll
        for (int kt = 0; kt < 16; ++kt) {
            float am[8], bn[8];
            *(float4*)&am[0] = *(const float4*)&As[kt][ty * 4];
            *(float4*)&am[4] = *(const float4*)&As[kt][64 + ty * 4];
            *(float4*)&bn[0] = *(const float4*)&Bs[kt][tx * 4];
            *(float4*)&bn[4] = *(const float4*)&Bs[kt][64 + tx * 4];
#pragma unroll
            for (int i = 0; i < 8; ++i)
#pragma unroll
                for (int j = 0; j < 8; ++j) acc[i][j] += am[i] * bn[j];
        }
    }

    float4 bias0 = *(const float4*)(bsrc + nOff + tx * 4);
    float4 bias1 = *(const float4*)(bsrc + nOff + 64 + tx * 4);
    const float bnv[8] = {bias0.x, bias0.y, bias0.z, bias0.w,
                          bias1.x, bias1.y, bias1.z, bias1.w};
#pragma unroll
    for (int i = 0; i < 8; ++i) {
        const int mg = Mbase + ty * 4 + (i & 3) + ((i >= 4) ? 64 : 0);
        float4 o0 = make_float4(acc[i][0] + bnv[0], acc[i][1] + bnv[1],
                                acc[i][2] + bnv[2], acc[i][3] + bnv[3]);
        float4 o1 = make_float4(acc[i][4] + bnv[4], acc[i][5] + bnv[5],
                                acc[i][6] + bnv[6], acc[i][7] + bnv[7]);
        *(float4*)(zx + (long long)mg * 2048 + Nbase + tx * 4) = o0;
        *(float4*)(zx + (long long)mg * 2048 + Nbase + 64 + tx * 4) = o1;
    }
}

// ---------------------------------------------------------------------------
// Kernel 1b: pack W_hh into per-(WG,thread) contiguous 512 B chunks:
// offset = (((d*4+q)*2 + half)*256 + j)*128 + k2
//   j = gate-row within WG (g = j>>6, e = q*64 + (j&63)), k = half*128+k2.
// lstm_team WG bx (bx&7 = d*4+q) thread tid reads chunk at tid*128.
// ---------------------------------------------------------------------------
__global__ __launch_bounds__(256) void pack_whh(
    const float* __restrict__ Whf, const float* __restrict__ Whb,
    float* __restrict__ pack)
{
    const int gid = blockIdx.x * 256 + threadIdx.x;   // 0..524287
    const int k2   = gid & 127;
    const int j    = (gid >> 7) & 255;
    const int half = (gid >> 15) & 1;
    const int q    = (gid >> 16) & 3;
    const int d    = (gid >> 18) & 1;
    const float* W = d ? Whb : Whf;
    const int g = j >> 6;
    const int e = q * 64 + (j & 63);
    pack[gid] = W[(g * 256 + e) * 256 + half * 128 + k2];
}

// ---------------------------------------------------------------------------
// Kernel 2: REGISTER-RESIDENT team LSTM.
// 256 WGs x 512 threads; bx: q = bx&3 (e-quarter), d = (bx>>2)&1, b = bx>>3.
// Thread owns HALF a gate-row = 32 float4. R5 lesson (VGPR_Count=88): the
// backend REMATERIALIZES loop-invariant global loads instead of keeping them
// in registers -> W was re-fetched from L1/L2 every step (2.2 us/step = the
// ~115 GB/s/CU L2-interface bound). Fix: empty inline-asm "+v" clobbers turn
// the W values into asm defs, which cannot be rematerialized; allocator must
// keep them resident (~175 VGPR < 256 cap from launch_bounds(512,2)).
// Exchange: tagged u64 {step,f32} ping-pong, relaxed AGENT atomics, one slot
// per polling thread (R2/R4/R5-proven). c state in wave-0 registers.
// ---------------------------------------------------------------------------
__global__ __launch_bounds__(512, 2) void lstm_team(
    const float* __restrict__ zx, const float* __restrict__ pack,
    const float* __restrict__ h0, const float* __restrict__ c0,
    unsigned long long* __restrict__ hx,   // [2 par][2 d][32 b][256 e]
    float* __restrict__ lstm_out)
{
    __shared__ float hS0[256];
    __shared__ float hS1[256];
    __shared__ float pS[512];

    const int tid = threadIdx.x;
    const int bx  = (int)blockIdx.x;
    const int q = bx & 3, d = (bx >> 2) & 1, b = bx >> 3;

    // --- W half-row into registers (one-time, coalesced) ---
    float4 wreg[32];
    {
        const float4* wrow = (const float4*)(pack + ((long long)(bx & 7) << 16)
                                             + tid * 128);
#pragma unroll
        for (int c = 0; c < 32; ++c) wreg[c] = wrow[c];
    }
    // Forbid rematerialization: values become asm outputs, not loads.
#pragma unroll
    for (int c = 0; c < 32; ++c) {
        asm volatile("" : "+v"(wreg[c].x), "+v"(wreg[c].y),
                          "+v"(wreg[c].z), "+v"(wreg[c].w));
    }

    const int half = tid >> 8;            // k-half this thread dots
    const long long hxbase = (long long)(d * 32 + b) * 256;
    const long long zbase = (long long)d * 1024 + q * 64 + (tid & 63);
    float creg = (tid < 64) ? c0[(d * 32 + b) * 256 + q * 64 + tid] : 0.0f;

    if (tid < 256) hS0[tid] = h0[(d * 32 + b) * 256 + tid];
    __syncthreads();

    for (int s = 0; s < T_LEN; ++s) {
        const int t = d ? (T_LEN - 1 - s) : s;

        // zx prefetch for gate wave (issued before dot; vmcnt hides latency)
        float zv0 = 0.f, zv1 = 0.f, zv2 = 0.f, zv3 = 0.f;
        if (tid < 64) {
            const float* zr = zx + (long long)(t * 32 + b) * 2048 + zbase;
            zv0 = zr[0]; zv1 = zr[256]; zv2 = zr[512]; zv3 = zr[768];
        }

        const float* h  = (s & 1) ? hS1 : hS0;
        float*       hN = (s & 1) ? hS0 : hS1;
        const float* hh = h + half * 128;   // wave-uniform -> LDS broadcast

        // --- half-dot from registers ---
        float a = 0.0f;
#pragma unroll
        for (int c = 0; c < 32; ++c) {
            const float4 hv = *(const float4*)(hh + c * 4);
            a += wreg[c].x * hv.x + wreg[c].y * hv.y
               + wreg[c].z * hv.z + wreg[c].w * hv.w;
        }
        pS[tid] = a;
        __syncthreads();

        const int parN = (s & 1) ^ 1;
        if (tid < 64) {
            const float zi = pS[tid]       + pS[tid + 256] + zv0;
            const float zf = pS[tid + 64]  + pS[tid + 320] + zv1;
            const float zg = pS[tid + 128] + pS[tid + 384] + zv2;
            const float zo = pS[tid + 192] + pS[tid + 448] + zv3;
            const float si = 1.0f / (1.0f + expf(-zi));
            const float sf = 1.0f / (1.0f + expf(-zf));
            const float so = 1.0f / (1.0f + expf(-zo));
            creg = sf * creg + si * tanhf(zg);
            const float hn = so * tanhf(creg);
            const int e = q * 64 + tid;
            hN[e] = hn;
            lstm_out[(long long)(t * 32 + b) * 512 + d * 256 + e] = hn;
            __hip_atomic_store(hx + (long long)parN * 16384 + hxbase + e,
                ((unsigned long long)(unsigned)(s + 1) << 32)
                    | (unsigned long long)__float_as_uint(hn),
                __ATOMIC_RELAXED, __HIP_MEMORY_SCOPE_AGENT);
        } else if (s < T_LEN - 1) {
            int e = -1;
            if (tid < 256) { if ((tid >> 6) != q) e = tid; }
            else if (tid < 320) { if (q != 0) e = tid - 256; }
            if (e >= 0) {
                const unsigned long long* slot =
                    hx + (long long)parN * 16384 + hxbase + e;
                unsigned long long v;
                do {
                    v = __hip_atomic_load(slot, __ATOMIC_RELAXED,
                                          __HIP_MEMORY_SCOPE_AGENT);
                } while ((unsigned)(v >> 32) != (unsigned)(s + 1));
                hN[e] = __uint_as_float((unsigned)v);
            }
        }
        __syncthreads();
    }
}

// ---------------------------------------------------------------------------
// Kernel 3: feats = lstm_out @ W_out^T + b_out
// ---------------------------------------------------------------------------
__global__ __launch_bounds__(256) void feats_kernel(
    const float* __restrict__ lstm_out, const float* __restrict__ W_out,
    const float* __restrict__ b_out, float* __restrict__ feats)
{
    const int gid = blockIdx.x * 256 + threadIdx.x;
    if (gid >= 8192 * NTAGS) return;
    const int row = gid / NTAGS;
    const int tag = gid - row * NTAGS;
    const float4* x = (const float4*)(lstm_out + (long long)row * 512);
    const float4* w = (const float4*)(W_out + (long long)tag * 512);
    float acc = b_out[tag];
#pragma unroll 4
    for (int k = 0; k < 128; ++k) {
        float4 a = x[k], bw = w[k];
        acc += a.x * bw.x + a.y * bw.y + a.z * bw.z + a.w * bw.w;
    }
    const int t = row >> 5, b = row & 31;
    feats[(long long)b * (T_LEN * NTAGS) + t * NTAGS + tag] = acc;
}

// ---------------------------------------------------------------------------
// Kernel 4: Viterbi per batch. 32 WGs x 64 threads.
// ---------------------------------------------------------------------------
__global__ __launch_bounds__(64) void viterbi_kernel(
    const float* __restrict__ feats, const float* __restrict__ trans,
    float* __restrict__ out)
{
    __shared__ float featS[T_LEN * NTAGS];
    __shared__ float transS[NTAGS * NTAGS];
    __shared__ float fvS[NTAGS];
    __shared__ unsigned char bpS[T_LEN][NTAGS];
    __shared__ float pathS[T_LEN];

    const int b = blockIdx.x;
    const int lane = threadIdx.x;

    {
        const float4* src = (const float4*)(feats + (long long)b * (T_LEN * NTAGS));
        float4* dst = (float4*)featS;
        for (int i = lane; i < (T_LEN * NTAGS) / 4; i += 64) dst[i] = src[i];
        for (int i = lane; i < NTAGS * NTAGS; i += 64) transS[i] = trans[i];
    }
    __syncthreads();

    float fv[NTAGS];
#pragma unroll
    for (int p = 0; p < NTAGS; ++p) fv[p] = (p == 10) ? 0.0f : NEGV;

    for (int t = 0; t < T_LEN; ++t) {
        if (lane < NTAGS) {
            float best = -3.4e38f; int bi = 0;
#pragma unroll
            for (int p = 0; p < NTAGS; ++p) {
                const float v = fv[p] + transS[lane * NTAGS + p];
                if (v > best) { best = v; bi = p; }
            }
            bpS[t][lane] = (unsigned char)bi;
            fvS[lane] = best + featS[t * NTAGS + lane];
        }
        __syncthreads();
#pragma unroll
        for (int p = 0; p < NTAGS; ++p) fv[p] = fvS[p];
        __syncthreads();
    }

    if (lane < NTAGS) fvS[lane] = fv[lane] + transS[11 * NTAGS + lane];
    __syncthreads();
    if (lane == 0) {
        float best = -3.4e38f; int bi = 0;
        for (int p = 0; p < NTAGS; ++p) {
            const float v = fvS[p];
            if (v > best) { best = v; bi = p; }
        }
        out[b] = best;
        int cur = bi;
        pathS[T_LEN - 1] = (float)cur;
        for (int tt = T_LEN - 2; tt >= 0; --tt) {
            cur = bpS[tt + 1][cur];
            pathS[tt] = (float)cur;
        }
    }
    __syncthreads();
    float* po = out + BATCH + (long long)b * T_LEN;
    for (int i = lane; i < T_LEN; i += 64) po[i] = pathS[i];
}

// ---------------------------------------------------------------------------
extern "C" void kernel_launch(void* const* d_in, const int* in_sizes, int n_in,
                              void* d_out, int out_size, void* d_ws, size_t ws_size,
                              hipStream_t stream)
{
    (void)in_sizes; (void)n_in; (void)out_size; (void)ws_size;
    const int*   sentence = (const int*)  d_in[0];
    const float* embed    = (const float*)d_in[1];
    const float* W_ih_f   = (const float*)d_in[2];
    const float* W_hh_f   = (const float*)d_in[3];
    const float* b_f      = (const float*)d_in[4];
    const float* W_ih_b   = (const float*)d_in[5];
    const float* W_hh_b   = (const float*)d_in[6];
    const float* b_b      = (const float*)d_in[7];
    const float* W_out    = (const float*)d_in[8];
    const float* b_out    = (const float*)d_in[9];
    const float* trans    = (const float*)d_in[10];
    const float* h0       = (const float*)d_in[11];
    const float* c0       = (const float*)d_in[12];
    float* out = (float*)d_out;

    char* ws = (char*)d_ws;
    float* zx       = (float*)ws; ws += (long long)8192 * 2048 * 4;   // 64 MB
    float* lstm_out = (float*)ws; ws += (long long)8192 * 512 * 4;    // 16 MB
    float* feats    = (float*)ws; ws += BATCH * T_LEN * NTAGS * 4;    // 384 KB
    float* pack     = (float*)ws; ws += (long long)524288 * 4;        // 2 MB
    unsigned long long* hx = (unsigned long long*)ws; ws += 2 * 16384 * 8; // 256 KB
    // hx re-poisoned to 0xAA before every launch -> tags invalid. No memset.

    pack_whh<<<2048, 256, 0, stream>>>(W_hh_f, W_hh_b, pack);
    gemm_zx<<<1024, 256, 0, stream>>>(sentence, embed, W_ih_f, W_ih_b, b_f, b_b, zx);
    lstm_team<<<256, 512, 0, stream>>>(zx, pack, h0, c0, hx, lstm_out);
    feats_kernel<<<384, 256, 0, stream>>>(lstm_out, W_out, b_out, feats);
    viterbi_kernel<<<32, 64, 0, stream>>>(feats, trans, out);
}